// Round 10
// baseline (229.060 us; speedup 1.0000x reference)
//
#include <hip/hip_runtime.h>
#include <cstddef>
#include <cstdint>

#define B_  4
#define N_  1024
#define D_  1024
#define H_  16
#define DH  64
#define M_  4096   // B_*N_

typedef __attribute__((ext_vector_type(4))) float   f32x4;
typedef __attribute__((ext_vector_type(8))) __bf16  bf16x8;
typedef __attribute__((ext_vector_type(4))) __bf16  bf16x4;

#define MFMA(a, b, c) __builtin_amdgcn_mfma_f32_16x16x32_bf16((a), (b), (c), 0, 0, 0)
#define GLDS(gp, lp) __builtin_amdgcn_global_load_lds( \
    (__attribute__((address_space(1))) void*)(gp),     \
    (__attribute__((address_space(3))) void*)(lp), 16, 0, 0)

// ---------------------------------------------------------------------------
// convert: fp32 -> bf16 for x (4Mi) and Wq/Wk/Wv/Wc (4x1Mi). [verified R3]
// ---------------------------------------------------------------------------
__global__ __launch_bounds__(256) void convert_k(
    const float* __restrict__ x,  const float* __restrict__ Wq,
    const float* __restrict__ Wk, const float* __restrict__ Wv,
    const float* __restrict__ Wc,
    __bf16* __restrict__ xb, __bf16* __restrict__ wqkvb,
    __bf16* __restrict__ wcb)
{
    const unsigned u = blockIdx.x * 256u + threadIdx.x;
    const unsigned e = u * 8u;
    const float* src;
    __bf16* dst;
    if (e < 4194304u) { src = x + e; dst = xb + e; }
    else {
        const unsigned t2 = e - 4194304u;
        const unsigned wsel = t2 >> 20;
        const unsigned wo = t2 & 1048575u;
        src = (wsel == 0 ? Wq : wsel == 1 ? Wk : wsel == 2 ? Wv : Wc) + wo;
        dst = (wsel < 3 ? wqkvb + (size_t)wsel * 1048576u : wcb) + wo;
    }
    const float4 f0 = *(const float4*)(src);
    const float4 f1 = *(const float4*)(src + 4);
    bf16x8 r;
    r[0] = (__bf16)f0.x; r[1] = (__bf16)f0.y; r[2] = (__bf16)f0.z; r[3] = (__bf16)f0.w;
    r[4] = (__bf16)f1.x; r[5] = (__bf16)f1.y; r[6] = (__bf16)f1.z; r[7] = (__bf16)f1.w;
    *(bf16x8*)dst = r;
}

// ---------------------------------------------------------------------------
// NT GEMM, bf16 MFMA — 64(M) x 128(N) tile, BK=32, frag-ordered GLDS staging
// + ds_read_b128 frags (R8-verified idioms, re-tiled for occupancy: QKV grid
// 1536 = 6 blocks/CU, final 512 = 2/CU; R9 showed MfmaUtil pinned at 17% at
// 1-3 blocks/CU -> barrier drains need co-resident blocks to hide, m114).
// Waves 2x2: wave rows wr*32 (mt 0..1), cols wc*64 (nt 0..3). 8 MFMA/iter.
// MODE 0: plain fp32 out  C[m, Nc=1024], A0 rows m, Wb rows e, bias b0.
// MODE 1: QKV. z=0,1 (q,k): A0=xb rows m, W slab z, HEADS out [B,H,N,Dh]
//   [epilogue verified R6-R9]. z=2: SWAPPED -> A=Wv rows e, B=xb rows m,
//   D[e][m]=V^T, written directly as vT [B,H,Dh,N] (lanes vary along m=n:
//   32B-contiguous stores), bias bv[e] row-indexed. Replaces transpose_v.
// ---------------------------------------------------------------------------
template <int MODE, typename OutT>
__global__ __launch_bounds__(256, 6) void gemm64(
    const __bf16* __restrict__ A0, const __bf16* __restrict__ Wb,
    const float* __restrict__ b0, const float* __restrict__ b1,
    const float* __restrict__ b2, OutT* __restrict__ Cb,
    OutT* __restrict__ vTp, int K)
{
    __shared__ __bf16 As[2048];   // 64x32, frag-ordered (4KB)
    __shared__ __bf16 Bs[4096];   // 128x32, frag-ordered (8KB)

    const int tid  = threadIdx.x;
    const int w    = tid >> 6;
    const int lane = tid & 63;
    const int quad = lane >> 4;
    const int l15  = lane & 15;
    const int wr   = w >> 1, wc = w & 1;

    const int z  = (MODE == 1) ? blockIdx.z : 0;
    const bool VT = (MODE == 1) && (z == 2);

    int m0, n0;
    if (VT) { m0 = (blockIdx.y & 15) * 64; n0 = (((blockIdx.y >> 4) * 8) + blockIdx.x) * 128; }
    else    { m0 = blockIdx.y * 64;        n0 = blockIdx.x * 128; }

    const __bf16* Aptr;
    const __bf16* Bptr;
    if (MODE == 1) {
        if (VT) { Aptr = Wb + (size_t)2 * D_ * D_; Bptr = A0; }
        else    { Aptr = A0; Bptr = Wb + (size_t)z * D_ * D_; }
    } else { Aptr = A0; Bptr = Wb; }

    // staging chunk decode (16B chunks, frag order c = T*64 + ko*16 + l)
    // A: 256 chunks (1/thread, c=tid); B: 512 chunks (c=tid, tid+256).
    const int Tt = tid >> 6, ko = (tid >> 4) & 3, l = tid & 15;
    const size_t aoff  = (size_t)(m0 + Tt * 16 + l) * K + ko * 8;
    const size_t boff1 = (size_t)(n0 + Tt * 16 + l) * K + ko * 8;
    const size_t boff2 = boff1 + (size_t)64 * K;   // chunks tid+256 -> rows +64
    __bf16* adst  = As + w * 512;                  // wave-uniform LDS bases
    __bf16* bdst1 = Bs + w * 512;
    __bf16* bdst2 = Bs + 2048 + w * 512;

    f32x4 acc[2][4];
    #pragma unroll
    for (int i = 0; i < 2; ++i)
        #pragma unroll
        for (int j = 0; j < 4; ++j)
            acc[i][j] = (f32x4){0.f, 0.f, 0.f, 0.f};

    for (int k0 = 0; k0 < K; k0 += 32) {
        GLDS(Aptr + aoff  + k0, adst);
        GLDS(Bptr + boff1 + k0, bdst1);
        GLDS(Bptr + boff2 + k0, bdst2);
        __syncthreads();

        bf16x8 af[2], bf[4];
        #pragma unroll
        for (int mt = 0; mt < 2; ++mt)
            af[mt] = *(const bf16x8*)(As + (((wr * 2 + mt) * 4 + quad) * 16 + l15) * 8);
        #pragma unroll
        for (int nt = 0; nt < 4; ++nt)
            bf[nt] = *(const bf16x8*)(Bs + (((wc * 4 + nt) * 4 + quad) * 16 + l15) * 8);
        #pragma unroll
        for (int mt = 0; mt < 2; ++mt)
            #pragma unroll
            for (int nt = 0; nt < 4; ++nt)
                acc[mt][nt] = MFMA(af[mt], bf[nt], acc[mt][nt]);
        __syncthreads();
    }

    // ---- epilogue: C-layout col = l15, row = quad*4 + r [verified R3-R9] ----
    if (!VT) {
        const float* bias = (MODE == 0) ? b0 : (z == 0 ? b0 : b1);
        float bvv[4];
        #pragma unroll
        for (int nt = 0; nt < 4; ++nt)
            bvv[nt] = bias[n0 + wc * 64 + nt * 16 + l15];
        #pragma unroll
        for (int mt = 0; mt < 2; ++mt) {
            #pragma unroll
            for (int r = 0; r < 4; ++r) {
                const int row = m0 + (wr * 2 + mt) * 16 + quad * 4 + r;
                #pragma unroll
                for (int nt = 0; nt < 4; ++nt) {
                    const int col = n0 + wc * 64 + nt * 16 + l15;
                    const float val = acc[mt][nt][r] + bvv[nt];
                    if (MODE == 1) {
                        OutT* C = Cb + (size_t)z * M_ * D_;
                        const size_t idx = (((size_t)(row >> 10) * H_ + (col >> 6)) * N_
                                            + (row & 1023)) * DH + (col & 63);
                        C[idx] = (OutT)val;
                    } else {
                        Cb[(size_t)row * D_ + col] = (OutT)val;
                    }
                }
            }
        }
    } else {
        // z==2: D[e][m] = V^T; write vT[B,H,Dh,N]; bias bv indexed by row=e
        #pragma unroll
        for (int mt = 0; mt < 2; ++mt) {
            #pragma unroll
            for (int r = 0; r < 4; ++r) {
                const int row = m0 + (wr * 2 + mt) * 16 + quad * 4 + r;  // e
                const float brow = b2[row];
                #pragma unroll
                for (int nt = 0; nt < 4; ++nt) {
                    const int col = n0 + wc * 64 + nt * 16 + l15;        // m
                    const float val = acc[mt][nt][r] + brow;
                    const size_t idx = (((size_t)(col >> 10) * H_ + (row >> 6)) * DH
                                        + (row & 63)) * N_ + (col & 1023);
                    vTp[idx] = (OutT)val;
                }
            }
        }
    }
}

// ---------------------------------------------------------------------------
// MFMA flash attention v5 — [verified R8/R9, byte-identical]. K/V tiles
// staged into LDS in fragment order via global_load_lds; ds_read_b128 frag
// reads; single-pass exp2 softmax; per-wave P LDS round-trip.
// ---------------------------------------------------------------------------
#define SP  68
#define SC2 0.04508422f   // (1/32) * log2(e)

__global__ __launch_bounds__(256, 4) void attn_mfma(
    const __bf16* __restrict__ qh, const __bf16* __restrict__ kh,
    const __bf16* __restrict__ vT, __bf16* __restrict__ ob)
{
    __shared__ __bf16 Ks[4096];        // 64 keys x 64 dh, frag-ordered (8KB)
    __shared__ __bf16 Vs[4096];        // 64 dh x 64 keys, frag-ordered (8KB)
    __shared__ float  Ps[4][16 * SP];  // per-wave P tile (17408B)

    const int tid  = threadIdx.x;
    const int w    = tid >> 6;
    const int lane = tid & 63;
    const int quad = lane >> 4;
    const int l15  = lane & 15;

    const int bh = blockIdx.x & 63;
    const int qt = blockIdx.x >> 6;
    const int b  = bh >> 4;
    const int h  = bh & 15;

    const __bf16* qp = qh + ((size_t)(b * H_ + h) * N_ + qt * 64 + w * 16 + l15) * DH + quad * 8;
    const bf16x8 qf0 = *(const bf16x8*)(qp);
    const bf16x8 qf1 = *(const bf16x8*)(qp + 32);

    const int c1 = tid, c2 = tid + 256;
    const int nt1 = c1 >> 7, ko1 = (c1 >> 4) & 7, l1 = c1 & 15;
    const int nt2 = c2 >> 7, ko2 = (c2 >> 4) & 7, l2 = c2 & 15;
    const __bf16* khead = kh + (size_t)(b * H_ + h) * N_ * DH;
    const __bf16* vhead = vT + (size_t)(b * H_ + h) * DH * N_;
    const size_t koff1 = (size_t)(nt1 * 16 + l1) * DH + ko1 * 8;
    const size_t koff2 = (size_t)(nt2 * 16 + l2) * DH + ko2 * 8;
    const size_t voff1 = (size_t)(nt1 * 16 + l1) * N_ + ko1 * 8;
    const size_t voff2 = (size_t)(nt2 * 16 + l2) * N_ + ko2 * 8;
    __bf16* ksdst1 = Ks + w * 512;
    __bf16* ksdst2 = Ks + 2048 + w * 512;
    __bf16* vsdst1 = Vs + w * 512;
    __bf16* vsdst2 = Vs + 2048 + w * 512;

    float psum[4] = {0.f, 0.f, 0.f, 0.f};
    f32x4 Ov[4];
    #pragma unroll
    for (int nt = 0; nt < 4; ++nt) Ov[nt] = (f32x4){0.f, 0.f, 0.f, 0.f};

    for (int kt = 0; kt < 16; ++kt) {
        GLDS(khead + (size_t)kt * 64 * DH + koff1, ksdst1);
        GLDS(khead + (size_t)kt * 64 * DH + koff2, ksdst2);
        GLDS(vhead + (size_t)kt * 64 + voff1, vsdst1);
        GLDS(vhead + (size_t)kt * 64 + voff2, vsdst2);
        __syncthreads();

        f32x4 sa[4];
        #pragma unroll
        for (int nt = 0; nt < 4; ++nt) {
            const bf16x8 kf0 = *(const bf16x8*)(Ks + (nt * 128 + quad * 16 + l15) * 8);
            const bf16x8 kf1 = *(const bf16x8*)(Ks + (nt * 128 + (quad + 4) * 16 + l15) * 8);
            sa[nt] = (f32x4){0.f, 0.f, 0.f, 0.f};
            sa[nt] = MFMA(qf0, kf0, sa[nt]);
            sa[nt] = MFMA(qf1, kf1, sa[nt]);
        }

        #pragma unroll
        for (int nt = 0; nt < 4; ++nt) {
            #pragma unroll
            for (int r = 0; r < 4; ++r) {
                const float p = __builtin_exp2f(sa[nt][r] * SC2);
                psum[r] += p;
                Ps[w][(quad * 4 + r) * SP + nt * 16 + l15] = p;
            }
        }

        #pragma unroll
        for (int kw = 0; kw < 2; ++kw) {
            const f32x4 pa = *(const f32x4*)&Ps[w][l15 * SP + kw * 32 + quad * 8];
            const f32x4 pb = *(const f32x4*)&Ps[w][l15 * SP + kw * 32 + quad * 8 + 4];
            bf16x8 pf;
            #pragma unroll
            for (int j = 0; j < 4; ++j) { pf[j] = (__bf16)pa[j]; pf[4 + j] = (__bf16)pb[j]; }
            #pragma unroll
            for (int nt = 0; nt < 4; ++nt) {
                const bf16x8 vf = *(const bf16x8*)(Vs + (nt * 128 + (kw * 4 + quad) * 16 + l15) * 8);
                Ov[nt] = MFMA(pf, vf, Ov[nt]);
            }
        }
        __syncthreads();
    }

    float lrow[4];
    #pragma unroll
    for (int r = 0; r < 4; ++r) {
        float lt = psum[r];
        lt += __shfl_xor(lt, 1);
        lt += __shfl_xor(lt, 2);
        lt += __shfl_xor(lt, 4);
        lt += __shfl_xor(lt, 8);
        lrow[r] = lt;
    }

    #pragma unroll
    for (int r = 0; r < 4; ++r) {
        const float inv = 1.0f / lrow[r];
        const int row = qt * 64 + w * 16 + quad * 4 + r;
        __bf16* op = ob + ((size_t)(b * H_ + h) * N_ + row) * DH + l15;
        #pragma unroll
        for (int nt = 0; nt < 4; ++nt)
            op[nt * 16] = (__bf16)(Ov[nt][r] * inv);
    }
}

// ---------------------------------------------------------------------------
extern "C" void kernel_launch(void* const* d_in, const int* in_sizes, int n_in,
                              void* d_out, int out_size, void* d_ws, size_t ws_size,
                              hipStream_t stream) {
    const float* x  = (const float*)d_in[0];
    const float* Wq = (const float*)d_in[1];
    const float* bq = (const float*)d_in[2];
    const float* Wk = (const float*)d_in[3];
    const float* bk = (const float*)d_in[4];
    const float* Wv = (const float*)d_in[5];
    const float* bv = (const float*)d_in[6];
    const float* Wc = (const float*)d_in[7];
    const float* bc = (const float*)d_in[8];
    float* out = (float*)d_out;

    // ws layout (48 MB total):
    //   [ 0, 8MB): xb (bf16 4Mi) -- dead after QKV GEMM, reused as obf
    //   [ 8,14MB): wqkvb  [14,16MB): wcb
    //   [16,40MB): qkvb (q,k slabs [B,H,N,Dh]; v slab unused)
    //   [40,48MB): vT [B,H,Dh,N] (written directly by gemm64 z=2)
    char* base = (char*)d_ws;
    __bf16* xb    = (__bf16*)(base);
    __bf16* wqkvb = (__bf16*)(base + (size_t)8  * 1048576);
    __bf16* wcb   = (__bf16*)(base + (size_t)14 * 1048576);
    __bf16* qkvb  = (__bf16*)(base + (size_t)16 * 1048576);
    __bf16* vTb   = (__bf16*)(base + (size_t)40 * 1048576);
    __bf16* obf   = (__bf16*)(base);   // overwrites xb after attn

    __bf16* qhb = qkvb;
    __bf16* khb = qkvb + (size_t)M_ * D_;

    convert_k<<<dim3(4096), dim3(256), 0, stream>>>(
        x, Wq, Wk, Wv, Wc, xb, wqkvb, wcb);

    // QKV: z=0,1 -> q,k heads; z=2 -> vT directly (swapped operands)
    gemm64<1, __bf16><<<dim3(8, 64, 3), dim3(256), 0, stream>>>(
        xb, wqkvb, bq, bk, bv, qkvb, vTb, D_);

    attn_mfma<<<dim3(1024), dim3(256), 0, stream>>>(qhb, khb, vTb, obf);

    gemm64<0, float><<<dim3(8, 64, 1), dim3(256), 0, stream>>>(
        obf, wcb, bc, bc, bc, out, out, D_);
}

// Round 11
// 208.511 us; speedup vs baseline: 1.0986x; 1.0986x over previous
//
#include <hip/hip_runtime.h>
#include <cstddef>
#include <cstdint>

#define B_  4
#define N_  1024
#define D_  1024
#define H_  16
#define DH  64
#define M_  4096   // B_*N_

typedef __attribute__((ext_vector_type(4))) float   f32x4;
typedef __attribute__((ext_vector_type(8))) __bf16  bf16x8;

#define MFMA(a, b, c) __builtin_amdgcn_mfma_f32_16x16x32_bf16((a), (b), (c), 0, 0, 0)
#define GLDS(gp, lp) __builtin_amdgcn_global_load_lds( \
    (__attribute__((address_space(1))) void*)(gp),     \
    (__attribute__((address_space(3))) void*)(lp), 16, 0, 0)

// ---------------------------------------------------------------------------
// convert: fp32 -> bf16 for x (4Mi) and Wq/Wk/Wv/Wc (4x1Mi). [verified R3]
// ---------------------------------------------------------------------------
__global__ __launch_bounds__(256) void convert_k(
    const float* __restrict__ x,  const float* __restrict__ Wq,
    const float* __restrict__ Wk, const float* __restrict__ Wv,
    const float* __restrict__ Wc,
    __bf16* __restrict__ xb, __bf16* __restrict__ wqkvb,
    __bf16* __restrict__ wcb)
{
    const unsigned u = blockIdx.x * 256u + threadIdx.x;
    const unsigned e = u * 8u;
    const float* src;
    __bf16* dst;
    if (e < 4194304u) { src = x + e; dst = xb + e; }
    else {
        const unsigned t2 = e - 4194304u;
        const unsigned wsel = t2 >> 20;
        const unsigned wo = t2 & 1048575u;
        src = (wsel == 0 ? Wq : wsel == 1 ? Wk : wsel == 2 ? Wv : Wc) + wo;
        dst = (wsel < 3 ? wqkvb + (size_t)wsel * 1048576u : wcb) + wo;
    }
    const float4 f0 = *(const float4*)(src);
    const float4 f1 = *(const float4*)(src + 4);
    bf16x8 r;
    r[0] = (__bf16)f0.x; r[1] = (__bf16)f0.y; r[2] = (__bf16)f0.z; r[3] = (__bf16)f0.w;
    r[4] = (__bf16)f1.x; r[5] = (__bf16)f1.y; r[6] = (__bf16)f1.z; r[7] = (__bf16)f1.w;
    *(bf16x8*)dst = r;
}

// ---------------------------------------------------------------------------
// QKV GEMM — R8-verified 128x128/BK=32 structure (56 us, the measured local
// optimum: R9 BK=64 neutral, R10 64x128@6/CU regressed to 79 us). z=0,1:
// q,k with HEADS epilogue [verified R6-R10]. z=2: swapped operands
// (A=Wv rows e, B=xb rows m) -> D[e][m]=V^T written directly as vT[B,H,Dh,N]
// [mapping verified R10]; block x/y roles swap for z=2 (8 e-tiles, 32 m-tiles).
// ---------------------------------------------------------------------------
__global__ __launch_bounds__(256, 3) void gemm_qkv(
    const __bf16* __restrict__ xb, const __bf16* __restrict__ Wb,
    const float* __restrict__ bq, const float* __restrict__ bk,
    const float* __restrict__ bv,
    __bf16* __restrict__ qk_out, __bf16* __restrict__ vT)
{
    __shared__ __bf16 As[4096];   // 128x32 bf16, frag-ordered (8KB)
    __shared__ __bf16 Bs[4096];

    const int tid  = threadIdx.x;
    const int w    = tid >> 6;
    const int lane = tid & 63;
    const int quad = lane >> 4;
    const int l15  = lane & 15;
    const int wr   = w >> 1, wc = w & 1;

    const int z  = blockIdx.z;
    const bool VT = (z == 2);

    int m0, n0;
    if (VT) { m0 = blockIdx.x * 128; n0 = blockIdx.y * 128; }   // m0 over e, n0 over m
    else    { m0 = blockIdx.y * 128; n0 = blockIdx.x * 128; }

    const __bf16* Ap = VT ? (Wb + (size_t)2 * D_ * D_) : xb;
    const __bf16* Bp = VT ? xb : (Wb + (size_t)z * D_ * D_);

    // staging chunk decode [verified R3-R8]: c -> row (c>>6)*16+(c&15), octet (c>>4)&3
    const int c1 = w * 128 + lane, c2 = c1 + 64;
    const size_t aoff1 = (size_t)(m0 + ((c1 >> 6) * 16) + (c1 & 15)) * D_ + (((c1 >> 4) & 3) * 8);
    const size_t aoff2 = (size_t)(m0 + ((c2 >> 6) * 16) + (c2 & 15)) * D_ + (((c2 >> 4) & 3) * 8);
    const size_t boff1 = (size_t)(n0 + ((c1 >> 6) * 16) + (c1 & 15)) * D_ + (((c1 >> 4) & 3) * 8);
    const size_t boff2 = (size_t)(n0 + ((c2 >> 6) * 16) + (c2 & 15)) * D_ + (((c2 >> 4) & 3) * 8);
    __bf16* asdst1 = As + w * 1024;
    __bf16* asdst2 = As + w * 1024 + 512;
    __bf16* bsdst1 = Bs + w * 1024;
    __bf16* bsdst2 = Bs + w * 1024 + 512;

    f32x4 acc[4][4];
    #pragma unroll
    for (int i = 0; i < 4; ++i)
        #pragma unroll
        for (int j = 0; j < 4; ++j)
            acc[i][j] = (f32x4){0.f, 0.f, 0.f, 0.f};

    for (int k0 = 0; k0 < D_; k0 += 32) {
        GLDS(Ap + aoff1 + k0, asdst1);
        GLDS(Ap + aoff2 + k0, asdst2);
        GLDS(Bp + boff1 + k0, bsdst1);
        GLDS(Bp + boff2 + k0, bsdst2);
        __syncthreads();

        bf16x8 af[4], bf[4];
        #pragma unroll
        for (int t = 0; t < 4; ++t) {
            af[t] = *(const bf16x8*)(As + ((wr * 4 + t) * 64 + quad * 16 + l15) * 8);
            bf[t] = *(const bf16x8*)(Bs + ((wc * 4 + t) * 64 + quad * 16 + l15) * 8);
        }
        #pragma unroll
        for (int mt = 0; mt < 4; ++mt)
            #pragma unroll
            for (int nt = 0; nt < 4; ++nt)
                acc[mt][nt] = MFMA(af[mt], bf[nt], acc[mt][nt]);
        __syncthreads();
    }

    if (!VT) {
        const float* bias = (z == 0) ? bq : bk;
        float bvv[4];
        #pragma unroll
        for (int nt = 0; nt < 4; ++nt)
            bvv[nt] = bias[n0 + wc * 64 + nt * 16 + l15];
        __bf16* C = qk_out + (size_t)z * M_ * D_;
        #pragma unroll
        for (int mt = 0; mt < 4; ++mt) {
            #pragma unroll
            for (int r = 0; r < 4; ++r) {
                const int row = m0 + wr * 64 + mt * 16 + quad * 4 + r;
                #pragma unroll
                for (int nt = 0; nt < 4; ++nt) {
                    const int col = n0 + wc * 64 + nt * 16 + l15;
                    const size_t idx = (((size_t)(row >> 10) * H_ + (col >> 6)) * N_
                                        + (row & 1023)) * DH + (col & 63);
                    C[idx] = (__bf16)(acc[mt][nt][r] + bvv[nt]);
                }
            }
        }
    } else {
        // D[e][m] = V^T; write vT[B,H,Dh,N]; bias bv[e=row]  [verified R10]
        #pragma unroll
        for (int mt = 0; mt < 4; ++mt) {
            #pragma unroll
            for (int r = 0; r < 4; ++r) {
                const int row = m0 + wr * 64 + mt * 16 + quad * 4 + r;   // e
                const float brow = bv[row];
                #pragma unroll
                for (int nt = 0; nt < 4; ++nt) {
                    const int col = n0 + wc * 64 + nt * 16 + l15;        // m
                    const size_t idx = (((size_t)(col >> 10) * H_ + (row >> 6)) * DH
                                        + (row & 63)) * N_ + (col & 1023);
                    vT[idx] = (__bf16)(acc[mt][nt][r] + brow);
                }
            }
        }
    }
}

// ---------------------------------------------------------------------------
// Final projection GEMM — R10's gemm64 MODE0 path (64x128, BK=32, 512 blocks
// = 2 blocks/CU; implied ~6 us faster than the 1/CU 128x128 variant).
// ---------------------------------------------------------------------------
__global__ __launch_bounds__(256, 6) void gemm_out(
    const __bf16* __restrict__ A0, const __bf16* __restrict__ Wb,
    const float* __restrict__ b0, float* __restrict__ Cb)
{
    __shared__ __bf16 As[2048];   // 64x32, frag-ordered (4KB)
    __shared__ __bf16 Bs[4096];   // 128x32, frag-ordered (8KB)

    const int tid  = threadIdx.x;
    const int w    = tid >> 6;
    const int lane = tid & 63;
    const int quad = lane >> 4;
    const int l15  = lane & 15;
    const int wr   = w >> 1, wc = w & 1;

    const int m0 = blockIdx.y * 64;
    const int n0 = blockIdx.x * 128;

    const int Tt = tid >> 6, ko = (tid >> 4) & 3, l = tid & 15;
    const size_t aoff  = (size_t)(m0 + Tt * 16 + l) * D_ + ko * 8;
    const size_t boff1 = (size_t)(n0 + Tt * 16 + l) * D_ + ko * 8;
    const size_t boff2 = boff1 + (size_t)64 * D_;
    __bf16* adst  = As + w * 512;
    __bf16* bdst1 = Bs + w * 512;
    __bf16* bdst2 = Bs + 2048 + w * 512;

    f32x4 acc[2][4];
    #pragma unroll
    for (int i = 0; i < 2; ++i)
        #pragma unroll
        for (int j = 0; j < 4; ++j)
            acc[i][j] = (f32x4){0.f, 0.f, 0.f, 0.f};

    for (int k0 = 0; k0 < D_; k0 += 32) {
        GLDS(A0 + aoff  + k0, adst);
        GLDS(Wb + boff1 + k0, bdst1);
        GLDS(Wb + boff2 + k0, bdst2);
        __syncthreads();

        bf16x8 af[2], bf[4];
        #pragma unroll
        for (int mt = 0; mt < 2; ++mt)
            af[mt] = *(const bf16x8*)(As + (((wr * 2 + mt) * 4 + quad) * 16 + l15) * 8);
        #pragma unroll
        for (int nt = 0; nt < 4; ++nt)
            bf[nt] = *(const bf16x8*)(Bs + (((wc * 4 + nt) * 4 + quad) * 16 + l15) * 8);
        #pragma unroll
        for (int mt = 0; mt < 2; ++mt)
            #pragma unroll
            for (int nt = 0; nt < 4; ++nt)
                acc[mt][nt] = MFMA(af[mt], bf[nt], acc[mt][nt]);
        __syncthreads();
    }

    float bvv[4];
    #pragma unroll
    for (int nt = 0; nt < 4; ++nt)
        bvv[nt] = b0[n0 + wc * 64 + nt * 16 + l15];
    #pragma unroll
    for (int mt = 0; mt < 2; ++mt) {
        #pragma unroll
        for (int r = 0; r < 4; ++r) {
            const int row = m0 + (wr * 2 + mt) * 16 + quad * 4 + r;
            #pragma unroll
            for (int nt = 0; nt < 4; ++nt) {
                const int col = n0 + wc * 64 + nt * 16 + l15;
                Cb[(size_t)row * D_ + col] = acc[mt][nt][r] + bvv[nt];
            }
        }
    }
}

// ---------------------------------------------------------------------------
// MFMA flash attention v5 — [verified R8-R10, byte-identical]. K/V staged
// into LDS in fragment order via global_load_lds; ds_read_b128 frag reads;
// single-pass exp2 softmax; per-wave P LDS round-trip.
// ---------------------------------------------------------------------------
#define SP  68
#define SC2 0.04508422f   // (1/32) * log2(e)

__global__ __launch_bounds__(256, 4) void attn_mfma(
    const __bf16* __restrict__ qh, const __bf16* __restrict__ kh,
    const __bf16* __restrict__ vT, __bf16* __restrict__ ob)
{
    __shared__ __bf16 Ks[4096];
    __shared__ __bf16 Vs[4096];
    __shared__ float  Ps[4][16 * SP];

    const int tid  = threadIdx.x;
    const int w    = tid >> 6;
    const int lane = tid & 63;
    const int quad = lane >> 4;
    const int l15  = lane & 15;

    const int bh = blockIdx.x & 63;
    const int qt = blockIdx.x >> 6;
    const int b  = bh >> 4;
    const int h  = bh & 15;

    const __bf16* qp = qh + ((size_t)(b * H_ + h) * N_ + qt * 64 + w * 16 + l15) * DH + quad * 8;
    const bf16x8 qf0 = *(const bf16x8*)(qp);
    const bf16x8 qf1 = *(const bf16x8*)(qp + 32);

    const int c1 = tid, c2 = tid + 256;
    const int nt1 = c1 >> 7, ko1 = (c1 >> 4) & 7, l1 = c1 & 15;
    const int nt2 = c2 >> 7, ko2 = (c2 >> 4) & 7, l2 = c2 & 15;
    const __bf16* khead = kh + (size_t)(b * H_ + h) * N_ * DH;
    const __bf16* vhead = vT + (size_t)(b * H_ + h) * DH * N_;
    const size_t koff1 = (size_t)(nt1 * 16 + l1) * DH + ko1 * 8;
    const size_t koff2 = (size_t)(nt2 * 16 + l2) * DH + ko2 * 8;
    const size_t voff1 = (size_t)(nt1 * 16 + l1) * N_ + ko1 * 8;
    const size_t voff2 = (size_t)(nt2 * 16 + l2) * N_ + ko2 * 8;
    __bf16* ksdst1 = Ks + w * 512;
    __bf16* ksdst2 = Ks + 2048 + w * 512;
    __bf16* vsdst1 = Vs + w * 512;
    __bf16* vsdst2 = Vs + 2048 + w * 512;

    float psum[4] = {0.f, 0.f, 0.f, 0.f};
    f32x4 Ov[4];
    #pragma unroll
    for (int nt = 0; nt < 4; ++nt) Ov[nt] = (f32x4){0.f, 0.f, 0.f, 0.f};

    for (int kt = 0; kt < 16; ++kt) {
        GLDS(khead + (size_t)kt * 64 * DH + koff1, ksdst1);
        GLDS(khead + (size_t)kt * 64 * DH + koff2, ksdst2);
        GLDS(vhead + (size_t)kt * 64 + voff1, vsdst1);
        GLDS(vhead + (size_t)kt * 64 + voff2, vsdst2);
        __syncthreads();

        f32x4 sa[4];
        #pragma unroll
        for (int nt = 0; nt < 4; ++nt) {
            const bf16x8 kf0 = *(const bf16x8*)(Ks + (nt * 128 + quad * 16 + l15) * 8);
            const bf16x8 kf1 = *(const bf16x8*)(Ks + (nt * 128 + (quad + 4) * 16 + l15) * 8);
            sa[nt] = (f32x4){0.f, 0.f, 0.f, 0.f};
            sa[nt] = MFMA(qf0, kf0, sa[nt]);
            sa[nt] = MFMA(qf1, kf1, sa[nt]);
        }

        #pragma unroll
        for (int nt = 0; nt < 4; ++nt) {
            #pragma unroll
            for (int r = 0; r < 4; ++r) {
                const float p = __builtin_exp2f(sa[nt][r] * SC2);
                psum[r] += p;
                Ps[w][(quad * 4 + r) * SP + nt * 16 + l15] = p;
            }
        }

        #pragma unroll
        for (int kw = 0; kw < 2; ++kw) {
            const f32x4 pa = *(const f32x4*)&Ps[w][l15 * SP + kw * 32 + quad * 8];
            const f32x4 pb = *(const f32x4*)&Ps[w][l15 * SP + kw * 32 + quad * 8 + 4];
            bf16x8 pf;
            #pragma unroll
            for (int j = 0; j < 4; ++j) { pf[j] = (__bf16)pa[j]; pf[4 + j] = (__bf16)pb[j]; }
            #pragma unroll
            for (int nt = 0; nt < 4; ++nt) {
                const bf16x8 vf = *(const bf16x8*)(Vs + (nt * 128 + (kw * 4 + quad) * 16 + l15) * 8);
                Ov[nt] = MFMA(pf, vf, Ov[nt]);
            }
        }
        __syncthreads();
    }

    float lrow[4];
    #pragma unroll
    for (int r = 0; r < 4; ++r) {
        float lt = psum[r];
        lt += __shfl_xor(lt, 1);
        lt += __shfl_xor(lt, 2);
        lt += __shfl_xor(lt, 4);
        lt += __shfl_xor(lt, 8);
        lrow[r] = lt;
    }

    #pragma unroll
    for (int r = 0; r < 4; ++r) {
        const float inv = 1.0f / lrow[r];
        const int row = qt * 64 + w * 16 + quad * 4 + r;
        __bf16* op = ob + ((size_t)(b * H_ + h) * N_ + row) * DH + l15;
        #pragma unroll
        for (int nt = 0; nt < 4; ++nt)
            op[nt * 16] = (__bf16)(Ov[nt][r] * inv);
    }
}

// ---------------------------------------------------------------------------
extern "C" void kernel_launch(void* const* d_in, const int* in_sizes, int n_in,
                              void* d_out, int out_size, void* d_ws, size_t ws_size,
                              hipStream_t stream) {
    const float* x  = (const float*)d_in[0];
    const float* Wq = (const float*)d_in[1];
    const float* bq = (const float*)d_in[2];
    const float* Wk = (const float*)d_in[3];
    const float* bk = (const float*)d_in[4];
    const float* Wv = (const float*)d_in[5];
    const float* bv = (const float*)d_in[6];
    const float* Wc = (const float*)d_in[7];
    const float* bc = (const float*)d_in[8];
    float* out = (float*)d_out;

    // ws layout (48 MB):
    //   [ 0, 8MB): xb (bf16 4Mi) -- dead after QKV GEMM, reused as obf
    //   [ 8,14MB): wqkvb  [14,16MB): wcb
    //   [16,40MB): qkvb (q,k slabs [B,H,N,Dh]; 3rd slab unused)
    //   [40,48MB): vT [B,H,Dh,N] (written directly by gemm_qkv z=2)
    char* base = (char*)d_ws;
    __bf16* xb    = (__bf16*)(base);
    __bf16* wqkvb = (__bf16*)(base + (size_t)8  * 1048576);
    __bf16* wcb   = (__bf16*)(base + (size_t)14 * 1048576);
    __bf16* qkvb  = (__bf16*)(base + (size_t)16 * 1048576);
    __bf16* vTb   = (__bf16*)(base + (size_t)40 * 1048576);
    __bf16* obf   = (__bf16*)(base);   // overwrites xb after attn

    __bf16* qhb = qkvb;
    __bf16* khb = qkvb + (size_t)M_ * D_;

    convert_k<<<dim3(4096), dim3(256), 0, stream>>>(
        x, Wq, Wk, Wv, Wc, xb, wqkvb, wcb);

    gemm_qkv<<<dim3(8, 32, 3), dim3(256), 0, stream>>>(
        xb, wqkvb, bq, bk, bv, qkvb, vTb);

    attn_mfma<<<dim3(1024), dim3(256), 0, stream>>>(qhb, khb, vTb, obf);

    gemm_out<<<dim3(8, 64, 1), dim3(256), 0, stream>>>(obf, wcb, bc, out);
}